// Round 5
// baseline (22769.308 us; speedup 1.0000x reference)
//
#include <hip/hip_runtime.h>
#include <hip/hip_cooperative_groups.h>
#include <hip/hip_fp16.h>
#include <math.h>

namespace cg = cooperative_groups;

#define H      4096
#define SEQ    2048
#define HOR    64
#define NBLK   256
#define NTHR   512
#define NWAVE  (NTHR / 64)
#define RPW    2            // rows per wave; 8 waves * 2 = 16 rows per block
#define J      16           // float4 chunks per lane per row: H/(64*4)

// control ints (offsets into cws = (int*)(ws + 2*H floats))
// flags[256]: one monotone int per block, 1 writer each.
// Line w (128B) = flags[w*32 .. w*32+32) = the flags of exactly the blocks
// whose h rows wave w gathers. Each wave polls ONE line with ONE coalesced
// request per poll -> 256 requests/line per ~0.5us poll period (~1 per 2ns),
// no storm (R0's storm was 8192 line-requests/poll).
#define FLAGS0   0

#define SMEM_H     (H * 4)               // 16384 B: h vector (fp32)
#define SMEM_R     (NWAVE * RPW * H * 2) // 131072 B: r_Wh rows (fp16, row-pair interleaved uint4)
#define SMEM_RED   128                   // red[8] (AR y) + pub[16] (h publish staging)
#define SMEM_BYTES (SMEM_H + SMEM_R + SMEM_RED)

typedef float f32x4_t __attribute__((ext_vector_type(4)));

// ---- fence-free L3-coherent point ops (sc0 sc1 = bypass L1+L2, served by
// memory-side Infinity Cache which is coherent across XCDs). ----
__device__ __forceinline__ void store_l3_i32(int* p, int v) {
    asm volatile("global_store_dword %0, %1, off sc0 sc1"
                 :: "v"(p), "v"(v) : "memory");
}
// NOTE: float4 (struct) as an asm INPUT fails ("indirect register inputs");
// ext_vector_type(4) maps to a contiguous VGPR quad and is accepted.
__device__ __forceinline__ void store_l3_f4(float4* p, float4 v) {
    f32x4_t w;
    w.x = v.x; w.y = v.y; w.z = v.z; w.w = v.w;
    asm volatile("global_store_dwordx4 %0, %1, off sc0 sc1"
                 :: "v"(p), "v"(w) : "memory");
}
__device__ __forceinline__ int load_l3_i32(const int* p) {
    int v;
    asm volatile("global_load_dword %0, %1, off sc0 sc1\n\t"
                 "s_waitcnt vmcnt(0)"
                 : "=v"(v) : "v"(p) : "memory");
    return v;
}
__device__ __forceinline__ float4 load_l3_f4(const float4* p) {
    float4 v;
    asm volatile("global_load_dwordx4 %0, %1, off sc0 sc1"
                 : "=v"(v) : "v"(p) : "memory");
    return v;
}
__device__ __forceinline__ void vm_drain() {
    asm volatile("s_waitcnt vmcnt(0)" ::: "memory");
}

__device__ __forceinline__ float wave_reduce(float v) {
#pragma unroll
    for (int o = 32; o > 0; o >>= 1) v += __shfl_xor(v, o, 64);
    return v;
}

__device__ __forceinline__ float dot4(float4 a, float4 b) {
    float s = a.x * b.x;
    s = fmaf(a.y, b.y, s);
    s = fmaf(a.z, b.z, s);
    s = fmaf(a.w, b.w, s);
    return s;
}

union H4U { uint2 u; __half h[4]; };

__device__ __forceinline__ uint2 pack4(float4 v) {
    H4U c;
    c.h[0] = __float2half_rn(v.x); c.h[1] = __float2half_rn(v.y);
    c.h[2] = __float2half_rn(v.z); c.h[3] = __float2half_rn(v.w);
    return c.u;
}

__device__ __forceinline__ float4 unpack4(uint2 p) {
    H4U c; c.u = p;
    return make_float4(__half2float(c.h[0]), __half2float(c.h[1]),
                       __half2float(c.h[2]), __half2float(c.h[3]));
}

// Fully weight-resident persistent GRU.
// R5 = R4 minus the aggregator relay (theory: agg-detect + det-line-visible +
// consumer-det-poll were ~2 serial L3 hops of pure detection overhead).
//  - publish (unchanged): epilogue -> LDS pub[16]; wave 0 lanes 0-3 write ONE
//    full 64B line per block; wave-0-only vmcnt drain; one flag store.
//  - detect (new): wave w polls flag line w directly -- the flags of exactly
//    the 32 blocks whose h lines wave w gathers. One coalesced line request
//    per wave per poll; waves proceed to their gather independently.
// Poison-safety: ws re-poisoned 0xAAAAAAAA = negative int < any t+1 >= 1, so
// flags need no init. Monotone all run; parity-free.
__global__ __launch_bounds__(NTHR, 2) void gru_kernel(
    const float* __restrict__ xseq,
    const float* __restrict__ uWx, const float* __restrict__ uWh, const float* __restrict__ ubv,
    const float* __restrict__ rWx, const float* __restrict__ rWh, const float* __restrict__ rbv,
    const float* __restrict__ wxv, const float* __restrict__ Whm, const float* __restrict__ bbv,
    const float* __restrict__ Vv,  const float* __restrict__ cv,
    float* __restrict__ out, float* __restrict__ ws)
{
    cg::grid_group grid = cg::this_grid();
    extern __shared__ unsigned char smem[];
    float* hF  = (float*)smem;                         // h, 4096 fp32
    uint4* rWm = (uint4*)(smem + SMEM_H);              // r_Wh fp16, row-pair interleaved
    float* red = (float*)(smem + SMEM_H + SMEM_R);     // 8 AR partials
    float* pub = red + NWAVE;                          // 16 h-publish slots

    const int tid  = threadIdx.x;
    const int wv   = tid >> 6;
    const int lane = tid & 63;
    const int bid  = blockIdx.x;
    const int r0   = bid * (NWAVE * RPW) + wv * RPW;
    const int r1   = r0 + 1;

    float* hA   = ws;
    float* hB   = ws + H;
    int*   cws  = (int*)(ws + 2 * H);
    int*   flags = cws + FLAGS0;

    // ---- one-time load: pin weights on-chip ----
    const float4* w0p = (const float4*)(Whm + (size_t)r0 * H);
    const float4* w1p = (const float4*)(Whm + (size_t)r1 * H);
    const float4* u0p = (const float4*)(uWh + (size_t)r0 * H);
    const float4* u1p = (const float4*)(uWh + (size_t)r1 * H);
    const float4* p0p = (const float4*)(rWh + (size_t)r0 * H);
    const float4* p1p = (const float4*)(rWh + (size_t)r1 * H);

    float4 wA[J], wB[J];
    uint2  uA[J], uB[J];
    uint4* rsm = rWm + wv * (H / 4);    // 1024 uint4 per wave (both rows)

#pragma unroll
    for (int j = 0; j < J; ++j) {
        const int idx = j * 64 + lane;
        wA[j] = w0p[idx];
        wB[j] = w1p[idx];
        uA[j] = pack4(u0p[idx]);
        uB[j] = pack4(u1p[idx]);
        const uint2 a = pack4(p0p[idx]);
        const uint2 b = pack4(p1p[idx]);
        rsm[idx] = make_uint4(a.x, a.y, b.x, b.y);
    }
#pragma unroll
    for (int j = 0; j < J; ++j) {
        asm volatile("" : "+v"(wA[j].x), "+v"(wA[j].y), "+v"(wA[j].z), "+v"(wA[j].w));
        asm volatile("" : "+v"(wB[j].x), "+v"(wB[j].y), "+v"(wB[j].z), "+v"(wB[j].w));
        asm volatile("" : "+v"(uA[j].x), "+v"(uA[j].y));
        asm volatile("" : "+v"(uB[j].x), "+v"(uB[j].y));
    }

    const float uwx0 = uWx[r0], uwx1 = uWx[r1], ub0 = ubv[r0], ub1 = ubv[r1];
    const float rwx0 = rWx[r0], rwx1 = rWx[r1], rb0 = rbv[r0], rb1 = rbv[r1];
    const float wx0  = wxv[r0], wx1  = wxv[r1], bb0 = bbv[r0], bb1 = bbv[r1];
    const float c0 = cv[0];

    // h0 = 0: each block seeds its own 64B line (coalesced, full-line write).
    if (tid < 4)
        store_l3_f4(&((float4*)hA)[bid * 4 + tid], make_float4(0.f, 0.f, 0.f, 0.f));

    grid.sync();   // one-time; its release includes a vmcnt(0) drain

    const float4* v4g = (const float4*)Vv;
    // wave w's flag word within line w (lanes duplicate across 32 words)
    const int* myflag = &flags[wv * 32 + (lane & 31)];
    const int gi = wv * 128 + lane * 2;   // this thread's 2 float4 slots of h

#pragma unroll 1
    for (int t = 0; t < SEQ + HOR; ++t) {
        // ---- per-wave direct detect: ONE coalesced line request per poll.
        // Divergent-exit while == wait until min over the 32 flags >= t.
        if (t > 0) {
            while (load_l3_i32(myflag) < t) {}
        }

        // ---- pull this wave's h slice (exactly its detected blocks) ----
        const float4* hin4 = (const float4*)((t & 1) ? hB : hA);
        float4* hout4 = (float4*)((t & 1) ? hA : hB);
        float4 s0 = load_l3_f4(&hin4[gi]);
        float4 s1 = load_l3_f4(&hin4[gi + 1]);
        vm_drain();
        ((float4*)hF)[gi]     = s0;
        ((float4*)hF)[gi + 1] = s1;
        __syncthreads();   // hF ready (also: all waves past previous publish)

        float x;
        if (t < SEQ) {
            x = xseq[t];
        } else {
            // y = v.h + c0, redundantly and identically in every block
            float4 a0 = ((const float4*)hF)[tid];
            float4 a1 = ((const float4*)hF)[tid + NTHR];
            float p = dot4(a0, v4g[tid]) + dot4(a1, v4g[tid + NTHR]);
            p = wave_reduce(p);
            if (lane == 0) red[wv] = p;
            __syncthreads();
            float y = c0;
#pragma unroll
            for (int w = 0; w < NWAVE; ++w) y += red[w];
            x = y;
            if (t > SEQ && bid == 0 && tid == 0) out[t - SEQ - 1] = y;
        }

        // ---- six resident row-dots against LDS h ----
        float au0 = 0.f, au1 = 0.f, ar0 = 0.f, ar1 = 0.f, aw0 = 0.f, aw1 = 0.f;
#pragma unroll
        for (int j = 0; j < J; ++j) {
            const int idx = j * 64 + lane;
            const float4 hv = ((const float4*)hF)[idx];
            aw0 = fmaf(wA[j].x, hv.x, aw0); aw0 = fmaf(wA[j].y, hv.y, aw0);
            aw0 = fmaf(wA[j].z, hv.z, aw0); aw0 = fmaf(wA[j].w, hv.w, aw0);
            aw1 = fmaf(wB[j].x, hv.x, aw1); aw1 = fmaf(wB[j].y, hv.y, aw1);
            aw1 = fmaf(wB[j].z, hv.z, aw1); aw1 = fmaf(wB[j].w, hv.w, aw1);
            const float4 ua4 = unpack4(uA[j]);
            au0 = fmaf(ua4.x, hv.x, au0); au0 = fmaf(ua4.y, hv.y, au0);
            au0 = fmaf(ua4.z, hv.z, au0); au0 = fmaf(ua4.w, hv.w, au0);
            const float4 ub4 = unpack4(uB[j]);
            au1 = fmaf(ub4.x, hv.x, au1); au1 = fmaf(ub4.y, hv.y, au1);
            au1 = fmaf(ub4.z, hv.z, au1); au1 = fmaf(ub4.w, hv.w, au1);
            const uint4 m = rsm[idx];
            const float4 ra4 = unpack4(make_uint2(m.x, m.y));
            ar0 = fmaf(ra4.x, hv.x, ar0); ar0 = fmaf(ra4.y, hv.y, ar0);
            ar0 = fmaf(ra4.z, hv.z, ar0); ar0 = fmaf(ra4.w, hv.w, ar0);
            const float4 rb4 = unpack4(make_uint2(m.z, m.w));
            ar1 = fmaf(rb4.x, hv.x, ar1); ar1 = fmaf(rb4.y, hv.y, ar1);
            ar1 = fmaf(rb4.z, hv.z, ar1); ar1 = fmaf(rb4.w, hv.w, ar1);
        }
        au0 = wave_reduce(au0); au1 = wave_reduce(au1);
        ar0 = wave_reduce(ar0); ar1 = wave_reduce(ar1);
        aw0 = wave_reduce(aw0); aw1 = wave_reduce(aw1);

        // ---- epilogue on lanes 0/1 -> LDS pub slots ----
        if (lane < 2) {
            const bool s = (lane == 1);
            const float adu = s ? au1 : au0;
            const float adr = s ? ar1 : ar0;
            const float adw = s ? aw1 : aw0;
            const float uwx = s ? uwx1 : uwx0, ubb = s ? ub1 : ub0;
            const float rwx = s ? rwx1 : rwx0, rbb = s ? rb1 : rb0;
            const float wxx = s ? wx1  : wx0,  bbb = s ? bb1 : bb0;
            const int   rr  = s ? r1 : r0;
            const float ho  = hF[rr];
            const float zu  = fmaf(uwx, x, adu + ubb);
            const float zr  = fmaf(rwx, x, adr + rbb);
            const float u   = 1.f / (1.f + expf(-zu));
            const float g   = 1.f / (1.f + expf(-zr));
            const float hh  = tanhf(fmaf(wxx, x, fmaf(g, adw, bbb)));
            pub[wv * RPW + (s ? 1 : 0)] = fmaf(u, hh - ho, ho);
        }
        __syncthreads();   // pub ready; also releases hF for next-step writes

        // ---- wave 0 only: single full-line h publish + flag ----
        if (wv == 0) {
            if (lane < 4) {
                const float4 pv = ((const float4*)pub)[lane];
                store_l3_f4(&hout4[bid * 4 + lane], pv);
            }
            vm_drain();   // wave-uniform: the block's h line is at L3
            if (lane == 0) store_l3_i32(&flags[bid], t + 1);
        }
        // no further barrier: next iteration's hF-ready barrier is collective
    }

    // preds[63] from final h (t=2111 odd wrote hA; flags all = 2112)
    if (bid == 0) {
        while (load_l3_i32(myflag) < SEQ + HOR) {}
        float4 s0 = load_l3_f4(&((const float4*)hA)[gi]);
        float4 s1 = load_l3_f4(&((const float4*)hA)[gi + 1]);
        vm_drain();
        ((float4*)hF)[gi]     = s0;
        ((float4*)hF)[gi + 1] = s1;
        __syncthreads();
        float4 a0 = ((const float4*)hF)[tid];
        float4 a1 = ((const float4*)hF)[tid + NTHR];
        float p = dot4(a0, v4g[tid]) + dot4(a1, v4g[tid + NTHR]);
        p = wave_reduce(p);
        if (lane == 0) red[wv] = p;
        __syncthreads();
        if (tid == 0) {
            float y = c0;
            for (int w = 0; w < NWAVE; ++w) y += red[w];
            out[HOR - 1] = y;
        }
    }
}

extern "C" void kernel_launch(void* const* d_in, const int* in_sizes, int n_in,
                              void* d_out, int out_size, void* d_ws, size_t ws_size,
                              hipStream_t stream) {
    const float* xseq = (const float*)d_in[0];
    const float* uWx  = (const float*)d_in[2];
    const float* uWh  = (const float*)d_in[3];
    const float* ubv  = (const float*)d_in[4];
    const float* rWx  = (const float*)d_in[5];
    const float* rWh  = (const float*)d_in[6];
    const float* rbv  = (const float*)d_in[7];
    const float* wxv  = (const float*)d_in[8];
    const float* Whm  = (const float*)d_in[9];
    const float* bbv  = (const float*)d_in[10];
    const float* Vv   = (const float*)d_in[11];
    const float* cv   = (const float*)d_in[12];
    float* out = (float*)d_out;
    float* ws  = (float*)d_ws;

    (void)hipFuncSetAttribute((const void*)gru_kernel,
                              hipFuncAttributeMaxDynamicSharedMemorySize, SMEM_BYTES);

    void* args[] = { &xseq, &uWx, &uWh, &ubv, &rWx, &rWh, &rbv,
                     &wxv, &Whm, &bbv, &Vv, &cv, &out, &ws };
    (void)hipLaunchCooperativeKernel((void*)gru_kernel, dim3(NBLK), dim3(NTHR),
                                     args, SMEM_BYTES, stream);
}

// Round 6
// 19863.524 us; speedup vs baseline: 1.1463x; 1.1463x over previous
//
#include <hip/hip_runtime.h>
#include <hip/hip_cooperative_groups.h>
#include <hip/hip_fp16.h>
#include <math.h>

namespace cg = cooperative_groups;

#define H      4096
#define SEQ    2048
#define HOR    64
#define NBLK   256
#define NTHR   512
#define NWAVE  (NTHR / 64)
#define RPW    2            // rows per wave; 8 waves * 2 = 16 rows per block
#define J      16           // float4 chunks per lane per row: H/(64*4)

#define NREP       8                     // replicas of the tagged h buffer
#define LINE_F     32                    // floats per 128B line (16 {h,tag} granules)
#define REP_F      (NBLK * LINE_F)       // floats per replica = 8192
#define BUF_F      (NREP * REP_F)        // floats per buffer   = 65536 (256 KB)

#define SMEM_H     (H * 4)               // 16384 B: h vector (fp32)
#define SMEM_R     (NWAVE * RPW * H * 2) // 131072 B: r_Wh rows (fp16, row-pair interleaved uint4)
#define SMEM_RED   128                   // red[8] (AR y) + pub[16] (h publish staging)
#define SMEM_BYTES (SMEM_H + SMEM_R + SMEM_RED)

typedef float f32x4_t __attribute__((ext_vector_type(4)));

// ---- fence-free L3-coherent point ops (sc0 sc1 = bypass L1+L2, served by
// memory-side Infinity Cache which is coherent across XCDs). ----
__device__ __forceinline__ void store_l3_f4(float* p, float a, float b, float c, float d) {
    f32x4_t w;
    w.x = a; w.y = b; w.z = c; w.w = d;
    asm volatile("global_store_dwordx4 %0, %1, off sc0 sc1"
                 :: "v"(p), "v"(w) : "memory");
}
__device__ __forceinline__ float4 load_l3_f4(const float4* p) {
    float4 v;
    asm volatile("global_load_dwordx4 %0, %1, off sc0 sc1"
                 : "=v"(v) : "v"(p) : "memory");
    return v;
}
__device__ __forceinline__ void vm_drain() {
    asm volatile("s_waitcnt vmcnt(0)" ::: "memory");
}

__device__ __forceinline__ float wave_reduce(float v) {
#pragma unroll
    for (int o = 32; o > 0; o >>= 1) v += __shfl_xor(v, o, 64);
    return v;
}

__device__ __forceinline__ float dot4(float4 a, float4 b) {
    float s = a.x * b.x;
    s = fmaf(a.y, b.y, s);
    s = fmaf(a.z, b.z, s);
    s = fmaf(a.w, b.w, s);
    return s;
}

union H4U { uint2 u; __half h[4]; };

__device__ __forceinline__ uint2 pack4(float4 v) {
    H4U c;
    c.h[0] = __float2half_rn(v.x); c.h[1] = __float2half_rn(v.y);
    c.h[2] = __float2half_rn(v.z); c.h[3] = __float2half_rn(v.w);
    return c.u;
}

__device__ __forceinline__ float4 unpack4(uint2 p) {
    H4U c; c.u = p;
    return make_float4(__half2float(c.h[0]), __half2float(c.h[1]),
                       __half2float(c.h[2]), __half2float(c.h[3]));
}

// Fully weight-resident persistent GRU.
// R6: tagged full-line granule exchange, replicated to keep lines cold.
//  - publish: epilogue -> LDS pub[16]; after barrier, wave 0 issues ONE
//    global_store_dwordx4: lane l writes 16B chunk (l&7) of replica (l>>3)'s
//    full 128B line {h,tag}x16 for this block. No drain, no flag, no relay.
//  - detect==gather: wave w of block b poll-loads its 4KB slice (32 source
//    blocks) from replica (b&7) -- 4 coalesced dwordx4/lane -- and exits
//    per-lane when all 8 embedded tags >= t. 32 readers/line (R5's 256-reader
//    producer-store stall avoided; R1's 512K-request scatter storm avoided).
//  - tags: float t (exact to 2112); ws poison 0xAAAAAAAA = -3e-13 < 0 fails
//    every check; double-buffer + monotone tags rule out WAR races.
__global__ __launch_bounds__(NTHR, 1) void gru_kernel(
    const float* __restrict__ xseq,
    const float* __restrict__ uWx, const float* __restrict__ uWh, const float* __restrict__ ubv,
    const float* __restrict__ rWx, const float* __restrict__ rWh, const float* __restrict__ rbv,
    const float* __restrict__ wxv, const float* __restrict__ Whm, const float* __restrict__ bbv,
    const float* __restrict__ Vv,  const float* __restrict__ cv,
    float* __restrict__ out, float* __restrict__ ws)
{
    cg::grid_group grid = cg::this_grid();
    extern __shared__ unsigned char smem[];
    float* hF  = (float*)smem;                         // h, 4096 fp32
    uint4* rWm = (uint4*)(smem + SMEM_H);              // r_Wh fp16, row-pair interleaved
    float* red = (float*)(smem + SMEM_H + SMEM_R);     // 8 AR partials
    float* pub = red + NWAVE;                          // 16 h-publish slots

    const int tid  = threadIdx.x;
    const int wv   = tid >> 6;
    const int lane = tid & 63;
    const int bid  = blockIdx.x;
    const int r0   = bid * (NWAVE * RPW) + wv * RPW;
    const int r1   = r0 + 1;

    float* hA = ws;            // tagged replicated buffer A (65536 floats)
    float* hB = ws + BUF_F;    // tagged replicated buffer B

    // ---- one-time load: pin weights on-chip ----
    const float4* w0p = (const float4*)(Whm + (size_t)r0 * H);
    const float4* w1p = (const float4*)(Whm + (size_t)r1 * H);
    const float4* u0p = (const float4*)(uWh + (size_t)r0 * H);
    const float4* u1p = (const float4*)(uWh + (size_t)r1 * H);
    const float4* p0p = (const float4*)(rWh + (size_t)r0 * H);
    const float4* p1p = (const float4*)(rWh + (size_t)r1 * H);

    float4 wA[J], wB[J];
    uint2  uA[J], uB[J];
    uint4* rsm = rWm + wv * (H / 4);    // 1024 uint4 per wave (both rows)

#pragma unroll
    for (int j = 0; j < J; ++j) {
        const int idx = j * 64 + lane;
        wA[j] = w0p[idx];
        wB[j] = w1p[idx];
        uA[j] = pack4(u0p[idx]);
        uB[j] = pack4(u1p[idx]);
        const uint2 a = pack4(p0p[idx]);
        const uint2 b = pack4(p1p[idx]);
        rsm[idx] = make_uint4(a.x, a.y, b.x, b.y);
    }
#pragma unroll
    for (int j = 0; j < J; ++j) {
        asm volatile("" : "+v"(wA[j].x), "+v"(wA[j].y), "+v"(wA[j].z), "+v"(wA[j].w));
        asm volatile("" : "+v"(wB[j].x), "+v"(wB[j].y), "+v"(wB[j].z), "+v"(wB[j].w));
        asm volatile("" : "+v"(uA[j].x), "+v"(uA[j].y));
        asm volatile("" : "+v"(uB[j].x), "+v"(uB[j].y));
    }

    const float uwx0 = uWx[r0], uwx1 = uWx[r1], ub0 = ubv[r0], ub1 = ubv[r1];
    const float rwx0 = rWx[r0], rwx1 = rWx[r1], rb0 = rbv[r0], rb1 = rbv[r1];
    const float wx0  = wxv[r0], wx1  = wxv[r1], bb0 = bbv[r0], bb1 = bbv[r1];
    const float c0 = cv[0];

    // ---- publish/gather address precompute ----
    // publish (wave 0): lane l -> replica (l>>3), 16B chunk (l&7) of block's line
    const int prep = lane >> 3, psub = lane & 7;
    const int pub_off = prep * REP_F + bid * LINE_F + psub * 4;   // floats
    // gather (wave w): lane l -> source block (32w + l/2), half (l&1) of its line
    const int gslot = wv * 32 + (lane >> 1);
    const int ghalf = lane & 1;
    const int gat_off = (bid & (NREP - 1)) * REP_F + gslot * LINE_F + ghalf * 16; // floats
    // hF staging: 8 h values -> float4 indices
    const int hf4 = gslot * 4 + ghalf * 2;

    // h0 = 0, tag = 0: seed all replicas of hA (one store instruction/block)
    if (wv == 0)
        store_l3_f4(hA + pub_off, 0.f, 0.f, 0.f, 0.f);

    grid.sync();   // one-time; its release includes a vmcnt(0) drain

    const float4* v4g = (const float4*)Vv;

#pragma unroll 1
    for (int t = 0; t < SEQ + HOR; ++t) {
        const float* hin  = (t & 1) ? hB : hA;
        float*       hout = (t & 1) ? hA : hB;
        const float tagf  = (float)t;
        const float tagf1 = (float)(t + 1);

        // ---- poll-gather: detection == data transfer, per-lane exit ----
        const float4* src = (const float4*)(hin + gat_off);
        float4 q0, q1, q2, q3;
        for (;;) {
            q0 = load_l3_f4(src);
            q1 = load_l3_f4(src + 1);
            q2 = load_l3_f4(src + 2);
            q3 = load_l3_f4(src + 3);
            vm_drain();
            const float mn = fminf(fminf(fminf(q0.y, q0.w), fminf(q1.y, q1.w)),
                                   fminf(fminf(q2.y, q2.w), fminf(q3.y, q3.w)));
            if (mn >= tagf) break;
        }
        ((float4*)hF)[hf4]     = make_float4(q0.x, q0.z, q1.x, q1.z);
        ((float4*)hF)[hf4 + 1] = make_float4(q2.x, q2.z, q3.x, q3.z);
        __syncthreads();   // hF ready (all stages done; prev-step hF dead)

        float x;
        if (t < SEQ) {
            x = xseq[t];
        } else {
            // y = v.h + c0, redundantly and identically in every block
            float4 a0 = ((const float4*)hF)[tid];
            float4 a1 = ((const float4*)hF)[tid + NTHR];
            float p = dot4(a0, v4g[tid]) + dot4(a1, v4g[tid + NTHR]);
            p = wave_reduce(p);
            if (lane == 0) red[wv] = p;
            __syncthreads();
            float y = c0;
#pragma unroll
            for (int w = 0; w < NWAVE; ++w) y += red[w];
            x = y;
            if (t > SEQ && bid == 0 && tid == 0) out[t - SEQ - 1] = y;
        }

        // ---- six resident row-dots against LDS h ----
        float au0 = 0.f, au1 = 0.f, ar0 = 0.f, ar1 = 0.f, aw0 = 0.f, aw1 = 0.f;
#pragma unroll
        for (int j = 0; j < J; ++j) {
            const int idx = j * 64 + lane;
            const float4 hv = ((const float4*)hF)[idx];
            aw0 = fmaf(wA[j].x, hv.x, aw0); aw0 = fmaf(wA[j].y, hv.y, aw0);
            aw0 = fmaf(wA[j].z, hv.z, aw0); aw0 = fmaf(wA[j].w, hv.w, aw0);
            aw1 = fmaf(wB[j].x, hv.x, aw1); aw1 = fmaf(wB[j].y, hv.y, aw1);
            aw1 = fmaf(wB[j].z, hv.z, aw1); aw1 = fmaf(wB[j].w, hv.w, aw1);
            const float4 ua4 = unpack4(uA[j]);
            au0 = fmaf(ua4.x, hv.x, au0); au0 = fmaf(ua4.y, hv.y, au0);
            au0 = fmaf(ua4.z, hv.z, au0); au0 = fmaf(ua4.w, hv.w, au0);
            const float4 ub4 = unpack4(uB[j]);
            au1 = fmaf(ub4.x, hv.x, au1); au1 = fmaf(ub4.y, hv.y, au1);
            au1 = fmaf(ub4.z, hv.z, au1); au1 = fmaf(ub4.w, hv.w, au1);
            const uint4 m = rsm[idx];
            const float4 ra4 = unpack4(make_uint2(m.x, m.y));
            ar0 = fmaf(ra4.x, hv.x, ar0); ar0 = fmaf(ra4.y, hv.y, ar0);
            ar0 = fmaf(ra4.z, hv.z, ar0); ar0 = fmaf(ra4.w, hv.w, ar0);
            const float4 rb4 = unpack4(make_uint2(m.z, m.w));
            ar1 = fmaf(rb4.x, hv.x, ar1); ar1 = fmaf(rb4.y, hv.y, ar1);
            ar1 = fmaf(rb4.z, hv.z, ar1); ar1 = fmaf(rb4.w, hv.w, ar1);
        }
        au0 = wave_reduce(au0); au1 = wave_reduce(au1);
        ar0 = wave_reduce(ar0); ar1 = wave_reduce(ar1);
        aw0 = wave_reduce(aw0); aw1 = wave_reduce(aw1);

        // ---- epilogue on lanes 0/1 -> LDS pub slots ----
        if (lane < 2) {
            const bool s = (lane == 1);
            const float adu = s ? au1 : au0;
            const float adr = s ? ar1 : ar0;
            const float adw = s ? aw1 : aw0;
            const float uwx = s ? uwx1 : uwx0, ubb = s ? ub1 : ub0;
            const float rwx = s ? rwx1 : rwx0, rbb = s ? rb1 : rb0;
            const float wxx = s ? wx1  : wx0,  bbb = s ? bb1 : bb0;
            const int   rr  = s ? r1 : r0;
            const float ho  = hF[rr];
            const float zu  = fmaf(uwx, x, adu + ubb);
            const float zr  = fmaf(rwx, x, adr + rbb);
            const float u   = 1.f / (1.f + expf(-zu));
            const float g   = 1.f / (1.f + expf(-zr));
            const float hh  = tanhf(fmaf(wxx, x, fmaf(g, adw, bbb)));
            pub[wv * RPW + (s ? 1 : 0)] = fmaf(u, hh - ho, ho);
        }
        __syncthreads();   // pub ready; also releases hF for next-step stages

        // ---- wave 0: ONE store instruction publishes 8 tagged replica lines
        if (wv == 0)
            store_l3_f4(hout + pub_off,
                        pub[psub * 2], tagf1, pub[psub * 2 + 1], tagf1);
        // no drain, no flag, no further barrier
    }

    // preds[63] from final h (t=2111 odd wrote hA with tag 2112); block 0 only
    if (bid == 0) {
        const float tagF = (float)(SEQ + HOR);
        const float4* src = (const float4*)(hA + gat_off);
        float4 q0, q1, q2, q3;
        for (;;) {
            q0 = load_l3_f4(src);
            q1 = load_l3_f4(src + 1);
            q2 = load_l3_f4(src + 2);
            q3 = load_l3_f4(src + 3);
            vm_drain();
            const float mn = fminf(fminf(fminf(q0.y, q0.w), fminf(q1.y, q1.w)),
                                   fminf(fminf(q2.y, q2.w), fminf(q3.y, q3.w)));
            if (mn >= tagF) break;
        }
        ((float4*)hF)[hf4]     = make_float4(q0.x, q0.z, q1.x, q1.z);
        ((float4*)hF)[hf4 + 1] = make_float4(q2.x, q2.z, q3.x, q3.z);
        __syncthreads();
        float4 a0 = ((const float4*)hF)[tid];
        float4 a1 = ((const float4*)hF)[tid + NTHR];
        float p = dot4(a0, v4g[tid]) + dot4(a1, v4g[tid + NTHR]);
        p = wave_reduce(p);
        if (lane == 0) red[wv] = p;
        __syncthreads();
        if (tid == 0) {
            float y = c0;
            for (int w = 0; w < NWAVE; ++w) y += red[w];
            out[HOR - 1] = y;
        }
    }
}

extern "C" void kernel_launch(void* const* d_in, const int* in_sizes, int n_in,
                              void* d_out, int out_size, void* d_ws, size_t ws_size,
                              hipStream_t stream) {
    const float* xseq = (const float*)d_in[0];
    const float* uWx  = (const float*)d_in[2];
    const float* uWh  = (const float*)d_in[3];
    const float* ubv  = (const float*)d_in[4];
    const float* rWx  = (const float*)d_in[5];
    const float* rWh  = (const float*)d_in[6];
    const float* rbv  = (const float*)d_in[7];
    const float* wxv  = (const float*)d_in[8];
    const float* Whm  = (const float*)d_in[9];
    const float* bbv  = (const float*)d_in[10];
    const float* Vv   = (const float*)d_in[11];
    const float* cv   = (const float*)d_in[12];
    float* out = (float*)d_out;
    float* ws  = (float*)d_ws;

    (void)hipFuncSetAttribute((const void*)gru_kernel,
                              hipFuncAttributeMaxDynamicSharedMemorySize, SMEM_BYTES);

    void* args[] = { &xseq, &uWx, &uWh, &ubv, &rWx, &rWh, &rbv,
                     &wxv, &Whm, &bbv, &Vv, &cv, &out, &ws };
    (void)hipLaunchCooperativeKernel((void*)gru_kernel, dim3(NBLK), dim3(NTHR),
                                     args, SMEM_BYTES, stream);
}

// Round 7
// 16713.144 us; speedup vs baseline: 1.3624x; 1.1885x over previous
//
#include <hip/hip_runtime.h>
#include <hip/hip_cooperative_groups.h>
#include <hip/hip_fp16.h>
#include <math.h>

namespace cg = cooperative_groups;

#define H      4096
#define SEQ    2048
#define HOR    64
#define NBLK   256
#define NTHR   512
#define NWAVE  (NTHR / 64)
#define RPW    2            // rows per wave; 8 waves * 2 = 16 rows per block
#define J      16           // float4 chunks per lane per row: H/(64*4)

#define NREP       8                     // replicas of the tagged h buffer
#define LINE_F     32                    // floats per 128B line (16 {h,tag} granules)
#define REP_F      (NBLK * LINE_F)       // floats per replica = 8192
#define BUF_F      (NREP * REP_F)        // floats per buffer   = 65536 (256 KB)

#define SMEM_H     (H * 4)               // 16384 B: h vector (fp32)
#define SMEM_R     (NWAVE * RPW * H * 2) // 131072 B: r_Wh rows (fp16, row-pair interleaved uint4)
#define SMEM_RED   128                   // red[8] + pub[16] + cnt
#define SMEM_BYTES (SMEM_H + SMEM_R + SMEM_RED)

typedef float f32x4_t __attribute__((ext_vector_type(4)));

// ---- fence-free L3-coherent point ops (sc0 sc1 = bypass L1+L2, served by
// memory-side Infinity Cache which is coherent across XCDs). ----
__device__ __forceinline__ void store_l3_f4(float* p, float a, float b, float c, float d) {
    f32x4_t w;
    w.x = a; w.y = b; w.z = c; w.w = d;
    asm volatile("global_store_dwordx4 %0, %1, off sc0 sc1"
                 :: "v"(p), "v"(w) : "memory");
}
__device__ __forceinline__ float4 load_l3_f4(const float4* p) {
    float4 v;
    asm volatile("global_load_dwordx4 %0, %1, off sc0 sc1"
                 : "=v"(v) : "v"(p) : "memory");
    return v;
}
__device__ __forceinline__ void vm_drain() {
    asm volatile("s_waitcnt vmcnt(0)" ::: "memory");
}

__device__ __forceinline__ float wave_reduce(float v) {
#pragma unroll
    for (int o = 32; o > 0; o >>= 1) v += __shfl_xor(v, o, 64);
    return v;
}

__device__ __forceinline__ float dot4(float4 a, float4 b) {
    float s = a.x * b.x;
    s = fmaf(a.y, b.y, s);
    s = fmaf(a.z, b.z, s);
    s = fmaf(a.w, b.w, s);
    return s;
}

union H4U { uint2 u; __half h[4]; };

__device__ __forceinline__ uint2 pack4(float4 v) {
    H4U c;
    c.h[0] = __float2half_rn(v.x); c.h[1] = __float2half_rn(v.y);
    c.h[2] = __float2half_rn(v.z); c.h[3] = __float2half_rn(v.w);
    return c.u;
}

__device__ __forceinline__ float4 unpack4(uint2 p) {
    H4U c; c.u = p;
    return make_float4(__half2float(c.h[0]), __half2float(c.h[1]),
                       __half2float(c.h[2]), __half2float(c.h[3]));
}

// Fully weight-resident persistent GRU.
// R7 = R6 (tagged replica-line exchange) + two changes:
//  (1) exponential poll backoff (retry, then s_sleep 1->2->4->8): cuts the
//      grid-wide poll sweep rate ~3-5x. Theory: the ~5us/step unexplained
//      sync cost is load-dependent latency inflation from ~40G line-req/s of
//      poll pressure on 256 hot L3 lines; every chain hop queues in it.
//  (2) last-arriving-wave publish: waves write pub[] then bump an LDS
//      counter; the wave seeing old==8t+7 (the step's critical-path wave)
//      immediately stores the 8 tagged replica lines BEFORE the barrier.
//      Removes barrier + wave-0 wakeup from the publish path.
// Tags: float t (exact to 2112); ws poison 0xAAAAAAAA = -3e-13 < 0 fails
// every tag check; double-buffer + monotone tags rule out WAR races.
__global__ __launch_bounds__(NTHR, 1) void gru_kernel(
    const float* __restrict__ xseq,
    const float* __restrict__ uWx, const float* __restrict__ uWh, const float* __restrict__ ubv,
    const float* __restrict__ rWx, const float* __restrict__ rWh, const float* __restrict__ rbv,
    const float* __restrict__ wxv, const float* __restrict__ Whm, const float* __restrict__ bbv,
    const float* __restrict__ Vv,  const float* __restrict__ cv,
    float* __restrict__ out, float* __restrict__ ws)
{
    cg::grid_group grid = cg::this_grid();
    extern __shared__ unsigned char smem[];
    float* hF  = (float*)smem;                         // h, 4096 fp32
    uint4* rWm = (uint4*)(smem + SMEM_H);              // r_Wh fp16, row-pair interleaved
    float* red = (float*)(smem + SMEM_H + SMEM_R);     // 8 AR partials
    float* pub = red + NWAVE;                          // 16 h-publish slots
    int*   cnt = (int*)(pub + NWAVE * RPW);            // wave-arrival counter

    const int tid  = threadIdx.x;
    const int wv   = tid >> 6;
    const int lane = tid & 63;
    const int bid  = blockIdx.x;
    const int r0   = bid * (NWAVE * RPW) + wv * RPW;
    const int r1   = r0 + 1;

    float* hA = ws;            // tagged replicated buffer A (65536 floats)
    float* hB = ws + BUF_F;    // tagged replicated buffer B

    if (tid == 0) *cnt = 0;

    // ---- one-time load: pin weights on-chip ----
    const float4* w0p = (const float4*)(Whm + (size_t)r0 * H);
    const float4* w1p = (const float4*)(Whm + (size_t)r1 * H);
    const float4* u0p = (const float4*)(uWh + (size_t)r0 * H);
    const float4* u1p = (const float4*)(uWh + (size_t)r1 * H);
    const float4* p0p = (const float4*)(rWh + (size_t)r0 * H);
    const float4* p1p = (const float4*)(rWh + (size_t)r1 * H);

    float4 wA[J], wB[J];
    uint2  uA[J], uB[J];
    uint4* rsm = rWm + wv * (H / 4);    // 1024 uint4 per wave (both rows)

#pragma unroll
    for (int j = 0; j < J; ++j) {
        const int idx = j * 64 + lane;
        wA[j] = w0p[idx];
        wB[j] = w1p[idx];
        uA[j] = pack4(u0p[idx]);
        uB[j] = pack4(u1p[idx]);
        const uint2 a = pack4(p0p[idx]);
        const uint2 b = pack4(p1p[idx]);
        rsm[idx] = make_uint4(a.x, a.y, b.x, b.y);
    }
#pragma unroll
    for (int j = 0; j < J; ++j) {
        asm volatile("" : "+v"(wA[j].x), "+v"(wA[j].y), "+v"(wA[j].z), "+v"(wA[j].w));
        asm volatile("" : "+v"(wB[j].x), "+v"(wB[j].y), "+v"(wB[j].z), "+v"(wB[j].w));
        asm volatile("" : "+v"(uA[j].x), "+v"(uA[j].y));
        asm volatile("" : "+v"(uB[j].x), "+v"(uB[j].y));
    }

    const float uwx0 = uWx[r0], uwx1 = uWx[r1], ub0 = ubv[r0], ub1 = ubv[r1];
    const float rwx0 = rWx[r0], rwx1 = rWx[r1], rb0 = rbv[r0], rb1 = rbv[r1];
    const float wx0  = wxv[r0], wx1  = wxv[r1], bb0 = bbv[r0], bb1 = bbv[r1];
    const float c0 = cv[0];

    // ---- publish/gather address precompute ----
    // publish: lane l -> replica (l>>3), 16B chunk (l&7) of this block's line
    const int prep = lane >> 3, psub = lane & 7;
    const int pub_off = prep * REP_F + bid * LINE_F + psub * 4;   // floats
    // gather (wave w): lane l -> source block (32w + l/2), half (l&1) of line
    const int gslot = wv * 32 + (lane >> 1);
    const int ghalf = lane & 1;
    const int gat_off = (bid & (NREP - 1)) * REP_F + gslot * LINE_F + ghalf * 16; // floats
    const int hf4 = gslot * 4 + ghalf * 2;   // hF float4 staging index

    // h0 = 0, tag = 0: seed all replicas of hA (one store instruction/block)
    if (wv == 0)
        store_l3_f4(hA + pub_off, 0.f, 0.f, 0.f, 0.f);

    grid.sync();   // one-time; its release includes a vmcnt(0) drain

    const float4* v4g = (const float4*)Vv;

#pragma unroll 1
    for (int t = 0; t < SEQ + HOR; ++t) {
        const float* hin  = (t & 1) ? hB : hA;
        float*       hout = (t & 1) ? hA : hB;
        const float tagf  = (float)t;
        const float tagf1 = (float)(t + 1);

        // ---- poll-gather with exponential backoff; per-lane exit ----
        const float4* src = (const float4*)(hin + gat_off);
        float4 q0, q1, q2, q3;
        int bk = 0;
        for (;;) {
            q0 = load_l3_f4(src);
            q1 = load_l3_f4(src + 1);
            q2 = load_l3_f4(src + 2);
            q3 = load_l3_f4(src + 3);
            vm_drain();
            const float mn = fminf(fminf(fminf(q0.y, q0.w), fminf(q1.y, q1.w)),
                                   fminf(fminf(q2.y, q2.w), fminf(q3.y, q3.w)));
            if (mn >= tagf) break;
            if      (bk == 0) { bk = 1; }
            else if (bk == 1) { __builtin_amdgcn_s_sleep(1); bk = 2; }
            else if (bk == 2) { __builtin_amdgcn_s_sleep(2); bk = 3; }
            else if (bk == 3) { __builtin_amdgcn_s_sleep(4); bk = 4; }
            else              { __builtin_amdgcn_s_sleep(8); }
        }
        ((float4*)hF)[hf4]     = make_float4(q0.x, q0.z, q1.x, q1.z);
        ((float4*)hF)[hf4 + 1] = make_float4(q2.x, q2.z, q3.x, q3.z);
        __syncthreads();   // hF ready (all stages done; prev-step hF dead)

        float x;
        if (t < SEQ) {
            x = xseq[t];
        } else {
            // y = v.h + c0, redundantly and identically in every block
            float4 a0 = ((const float4*)hF)[tid];
            float4 a1 = ((const float4*)hF)[tid + NTHR];
            float p = dot4(a0, v4g[tid]) + dot4(a1, v4g[tid + NTHR]);
            p = wave_reduce(p);
            if (lane == 0) red[wv] = p;
            __syncthreads();
            float y = c0;
#pragma unroll
            for (int w = 0; w < NWAVE; ++w) y += red[w];
            x = y;
            if (t > SEQ && bid == 0 && tid == 0) out[t - SEQ - 1] = y;
        }

        // ---- six resident row-dots against LDS h ----
        float au0 = 0.f, au1 = 0.f, ar0 = 0.f, ar1 = 0.f, aw0 = 0.f, aw1 = 0.f;
#pragma unroll
        for (int j = 0; j < J; ++j) {
            const int idx = j * 64 + lane;
            const float4 hv = ((const float4*)hF)[idx];
            aw0 = fmaf(wA[j].x, hv.x, aw0); aw0 = fmaf(wA[j].y, hv.y, aw0);
            aw0 = fmaf(wA[j].z, hv.z, aw0); aw0 = fmaf(wA[j].w, hv.w, aw0);
            aw1 = fmaf(wB[j].x, hv.x, aw1); aw1 = fmaf(wB[j].y, hv.y, aw1);
            aw1 = fmaf(wB[j].z, hv.z, aw1); aw1 = fmaf(wB[j].w, hv.w, aw1);
            const float4 ua4 = unpack4(uA[j]);
            au0 = fmaf(ua4.x, hv.x, au0); au0 = fmaf(ua4.y, hv.y, au0);
            au0 = fmaf(ua4.z, hv.z, au0); au0 = fmaf(ua4.w, hv.w, au0);
            const float4 ub4 = unpack4(uB[j]);
            au1 = fmaf(ub4.x, hv.x, au1); au1 = fmaf(ub4.y, hv.y, au1);
            au1 = fmaf(ub4.z, hv.z, au1); au1 = fmaf(ub4.w, hv.w, au1);
            const uint4 m = rsm[idx];
            const float4 ra4 = unpack4(make_uint2(m.x, m.y));
            ar0 = fmaf(ra4.x, hv.x, ar0); ar0 = fmaf(ra4.y, hv.y, ar0);
            ar0 = fmaf(ra4.z, hv.z, ar0); ar0 = fmaf(ra4.w, hv.w, ar0);
            const float4 rb4 = unpack4(make_uint2(m.z, m.w));
            ar1 = fmaf(rb4.x, hv.x, ar1); ar1 = fmaf(rb4.y, hv.y, ar1);
            ar1 = fmaf(rb4.z, hv.z, ar1); ar1 = fmaf(rb4.w, hv.w, ar1);
        }
        au0 = wave_reduce(au0); au1 = wave_reduce(au1);
        ar0 = wave_reduce(ar0); ar1 = wave_reduce(ar1);
        aw0 = wave_reduce(aw0); aw1 = wave_reduce(aw1);

        // ---- epilogue on lanes 0/1 -> LDS pub slots ----
        if (lane < 2) {
            const bool s = (lane == 1);
            const float adu = s ? au1 : au0;
            const float adr = s ? ar1 : ar0;
            const float adw = s ? aw1 : aw0;
            const float uwx = s ? uwx1 : uwx0, ubb = s ? ub1 : ub0;
            const float rwx = s ? rwx1 : rwx0, rbb = s ? rb1 : rb0;
            const float wxx = s ? wx1  : wx0,  bbb = s ? bb1 : bb0;
            const int   rr  = s ? r1 : r0;
            const float ho  = hF[rr];
            const float zu  = fmaf(uwx, x, adu + ubb);
            const float zr  = fmaf(rwx, x, adr + rbb);
            const float u   = 1.f / (1.f + expf(-zu));
            const float g   = 1.f / (1.f + expf(-zr));
            const float hh  = tanhf(fmaf(wxx, x, fmaf(g, adw, bbb)));
            pub[wv * RPW + (s ? 1 : 0)] = fmaf(u, hh - ho, ho);
        }
        // ensure this wave's pub writes are in LDS before its arrival bump
        asm volatile("s_waitcnt lgkmcnt(0)" ::: "memory");
        int old = 0;
        if (lane == 0) old = atomicAdd(cnt, 1);
        old = __shfl(old, 0, 64);
        if (old == 8 * t + 7) {
            // last-arriving wave: publish the block's 8 tagged replica lines
            const float h0v = pub[psub * 2], h1v = pub[psub * 2 + 1];
            store_l3_f4(hout + pub_off, h0v, tagf1, h1v, tagf1);
        }
        __syncthreads();   // releases hF + pub for next-step stages
        // no drain, no flag, publish already in flight
    }

    // preds[63] from final h (t=2111 odd wrote hA with tag 2112); block 0 only
    if (bid == 0) {
        const float tagF = (float)(SEQ + HOR);
        const float4* src = (const float4*)(hA + gat_off);
        float4 q0, q1, q2, q3;
        int bk = 0;
        for (;;) {
            q0 = load_l3_f4(src);
            q1 = load_l3_f4(src + 1);
            q2 = load_l3_f4(src + 2);
            q3 = load_l3_f4(src + 3);
            vm_drain();
            const float mn = fminf(fminf(fminf(q0.y, q0.w), fminf(q1.y, q1.w)),
                                   fminf(fminf(q2.y, q2.w), fminf(q3.y, q3.w)));
            if (mn >= tagF) break;
            if      (bk == 0) { bk = 1; }
            else              { __builtin_amdgcn_s_sleep(2); }
        }
        ((float4*)hF)[hf4]     = make_float4(q0.x, q0.z, q1.x, q1.z);
        ((float4*)hF)[hf4 + 1] = make_float4(q2.x, q2.z, q3.x, q3.z);
        __syncthreads();
        float4 a0 = ((const float4*)hF)[tid];
        float4 a1 = ((const float4*)hF)[tid + NTHR];
        float p = dot4(a0, v4g[tid]) + dot4(a1, v4g[tid + NTHR]);
        p = wave_reduce(p);
        if (lane == 0) red[wv] = p;
        __syncthreads();
        if (tid == 0) {
            float y = c0;
            for (int w = 0; w < NWAVE; ++w) y += red[w];
            out[HOR - 1] = y;
        }
    }
}

extern "C" void kernel_launch(void* const* d_in, const int* in_sizes, int n_in,
                              void* d_out, int out_size, void* d_ws, size_t ws_size,
                              hipStream_t stream) {
    const float* xseq = (const float*)d_in[0];
    const float* uWx  = (const float*)d_in[2];
    const float* uWh  = (const float*)d_in[3];
    const float* ubv  = (const float*)d_in[4];
    const float* rWx  = (const float*)d_in[5];
    const float* rWh  = (const float*)d_in[6];
    const float* rbv  = (const float*)d_in[7];
    const float* wxv  = (const float*)d_in[8];
    const float* Whm  = (const float*)d_in[9];
    const float* bbv  = (const float*)d_in[10];
    const float* Vv   = (const float*)d_in[11];
    const float* cv   = (const float*)d_in[12];
    float* out = (float*)d_out;
    float* ws  = (float*)d_ws;

    (void)hipFuncSetAttribute((const void*)gru_kernel,
                              hipFuncAttributeMaxDynamicSharedMemorySize, SMEM_BYTES);

    void* args[] = { &xseq, &uWx, &uWh, &ubv, &rWx, &rWh, &rbv,
                     &wxv, &Whm, &bbv, &Vv, &cv, &out, &ws };
    (void)hipLaunchCooperativeKernel((void*)gru_kernel, dim3(NBLK), dim3(NTHR),
                                     args, SMEM_BYTES, stream);
}